// Round 8
// baseline (121.535 us; speedup 1.0000x reference)
//
#include <hip/hip_runtime.h>
#include <math.h>

#define C_   256
#define WH   4096

typedef _Float16 f16x8 __attribute__((ext_vector_type(8)));
typedef _Float16 f16x2 __attribute__((ext_vector_type(2)));
typedef float    f32x4 __attribute__((ext_vector_type(4)));

// ---------------- workspace layout (floats) ----------------
// qbn   : [16][16][4096]             @ 0          (1,048,576)
// S     : [256]  (atomic Σexp)       @ 1,048,576  (256)
// Wt    : [16][4096]                 @ 1,048,832  (65,536)
// Mpart : [16][32 s5][2 t][16][256]  @ 1,114,368  (4,194,304)  t=0:U(unnorm) t=1:T

// ---- Wt (summed spatial conv weight) + S zeroing. 64 blocks. ----
__global__ __launch_bounds__(256) void wt_kernel(const float* __restrict__ emb,
                                                 float* __restrict__ Wt,
                                                 float* __restrict__ S)
{
    int wb = blockIdx.x;
    if (threadIdx.x < 4) S[wb * 4 + threadIdx.x] = 0.f;   // 64*4 = 256, disjoint
    int hk = wb >> 2, quarter = wb & 3;
    int h = hk >> 2, k = hk & 3;
    const float* e = emb + (size_t)(k * 4 + h) * 529;     // emb[k][h][0][0][i][j]
    __shared__ float colsum[23][64];
    for (int t = threadIdx.x; t < 23 * 64; t += 256) {
        int i = t / 64, q = t % 64;
        int jlo = max(0, q - 52), jhi = min(22, q + 11);
        float s = 0.f;
        for (int j = jlo; j <= jhi; ++j) s += e[i * 23 + j];
        colsum[i][q] = s;
    }
    __syncthreads();
    for (int tt = threadIdx.x; tt < 1024; tt += 256) {
        int t = quarter * 1024 + tt;
        int p = t >> 6, q = t & 63;
        int ilo = max(0, p - 52), ihi = min(22, p + 11);
        float s = 0.f;
        for (int i = ilo; i <= ihi; ++i) s += colsum[i][q];
        Wt[(size_t)hk * WH + t] = s;
    }
}

// ---- FUSED proj + U/T MFMA. Grid 512 = (b, s5 of 128 px), 512 thr.
// Phase 1: wave w (0..7) computes 4 rows of [16 q ; 16 k] for this window
//   (lane = 2 px, float2 global x reads = the only HBM x read). q -> qbn.
//   k -> kk -> exp(kk) UNNORMALIZED (softmax max-shift is optional; |kk|<~7)
//   -> fp16 ebuf + atomicAdd partial sums into S.
// Phase 2: round-7-proven MFMA core: A_U = ebuf rows, A_T = Wt rows
//   (both [16][136] fp16: banks 4*(r+g) mod 32 -> exact 8-lane/quad floor),
//   B = xls[256][72] staged per 64-px chunk (verbatim round-7; L2-hot).
// Tail: write U and T 16x256 fp32 tiles (1/S applied later in out). ----
__global__ __launch_bounds__(512) void main_kernel(
    const float* __restrict__ x,
    const float* __restrict__ qw, const float* __restrict__ kw,
    const float* __restrict__ qg, const float* __restrict__ qb,
    const float* __restrict__ qm, const float* __restrict__ qv,
    const float* __restrict__ kg, const float* __restrict__ kb,
    const float* __restrict__ km, const float* __restrict__ kv,
    const float* __restrict__ Wt,
    float* __restrict__ qbn, float* __restrict__ S, float* __restrict__ Mpart)
{
    __shared__ _Float16 xls[256][72];    // 36,864 B : X rows (c), 64 px per chunk
    __shared__ _Float16 ebuf[16][136];   //  4,352 B : exp(kk) rows, 128 px
    __shared__ _Float16 wtbuf[16][136];  //  4,352 B : Wt rows, 128 px
    int t = threadIdx.x, lane = t & 63;
    int w = __builtin_amdgcn_readfirstlane(t >> 6);   // 0..7, wave-uniform
    int b = blockIdx.x >> 5, s5 = blockIdx.x & 31;
    int win = s5 * 128;

    // ---- stage wtbuf (one-time) ----
    if (t < 256) {
        int r = t >> 4, xo = (t & 15) * 8;
        const float* src = Wt + (size_t)r * WH + win + xo;
        float4 u = *(const float4*)src, u2 = *(const float4*)(src + 4);
        _Float16* d = &wtbuf[r][xo];
        d[0]=(_Float16)u.x;  d[1]=(_Float16)u.y;  d[2]=(_Float16)u.z;  d[3]=(_Float16)u.w;
        d[4]=(_Float16)u2.x; d[5]=(_Float16)u2.y; d[6]=(_Float16)u2.z; d[7]=(_Float16)u2.w;
    }

    // ---- phase 1: projection (wave = 4 rows, lane = 2 px) ----
    {
        int isK = w >> 2;
        int r0 = (w & 3) * 4;
        const float* wsrc = isK ? kw : qw;
        const float* w0 = wsrc + (size_t)(r0 + 0) * 256;
        const float* w1 = wsrc + (size_t)(r0 + 1) * 256;
        const float* w2 = wsrc + (size_t)(r0 + 2) * 256;
        const float* w3 = wsrc + (size_t)(r0 + 3) * 256;
        float2 a0 = {0,0}, a1 = {0,0}, a2 = {0,0}, a3 = {0,0};
        const float* xb = x + (size_t)b * C_ * WH + win + lane * 2;
#pragma unroll 8
        for (int c = 0; c < 256; ++c) {
            float2 xv = *(const float2*)(xb + (size_t)c * WH);
            float f0 = w0[c], f1 = w1[c], f2 = w2[c], f3 = w3[c];
            a0.x += xv.x*f0; a0.y += xv.y*f0;
            a1.x += xv.x*f1; a1.y += xv.y*f1;
            a2.x += xv.x*f2; a2.y += xv.y*f2;
            a3.x += xv.x*f3; a3.y += xv.y*f3;
        }
        float2 acc2[4] = {a0, a1, a2, a3};
        if (!isK) {
#pragma unroll
            for (int i = 0; i < 4; ++i) {
                int hk = r0 + i;
                float s  = qg[hk] * rsqrtf(qv[hk] + 1e-5f);
                float tq = qb[hk] - qm[hk] * s;
                float2 o; o.x = acc2[i].x * s + tq; o.y = acc2[i].y * s + tq;
                *(float2*)(qbn + ((size_t)b * 16 + hk) * WH + win + lane * 2) = o;
            }
        } else {
#pragma unroll
            for (int i = 0; i < 4; ++i) {
                int hk = r0 + i;
                float s2 = kg[hk] * rsqrtf(kv[hk] + 1e-5f);
                float tk = kb[hk] - km[hk] * s2;
                float e0 = __expf(acc2[i].x * s2 + tk);
                float e1 = __expf(acc2[i].y * s2 + tk);
                f16x2 p; p[0] = (_Float16)e0; p[1] = (_Float16)e1;
                *(f16x2*)&ebuf[hk][lane * 2] = p;
                float ssum = e0 + e1;
#pragma unroll
                for (int off = 32; off; off >>= 1) ssum += __shfl_xor(ssum, off, 64);
                if (lane == 0) atomicAdd(&S[b * 16 + hk], ssum);
            }
        }
    }

    // ---- phase 2: MFMA (round-7 core) ----
    int r16 = lane & 15, g = lane >> 4;
    int n0 = w * 32;
    int sc = t >> 1, shalf = t & 1;
    f32x4 acc00 = {0.f,0.f,0.f,0.f}, acc01 = {0.f,0.f,0.f,0.f};
    f32x4 acc10 = {0.f,0.f,0.f,0.f}, acc11 = {0.f,0.f,0.f,0.f};

    for (int ch = 0; ch < 2; ++ch) {
        int kbase = win + ch * 64;
        __syncthreads();          // prev reads done; (ch=0) ebuf/wtbuf/phase1 visible
        {   // stage X: 256 rows x 64 px (thread: row sc, 32-px half) — L2-hot re-read
            const float* xp = x + ((size_t)b * C_ + sc) * WH + kbase + shalf * 32;
#pragma unroll
            for (int j = 0; j < 4; ++j) {
                float4 u  = *(const float4*)(xp + j * 8);
                float4 u2 = *(const float4*)(xp + j * 8 + 4);
                f16x8 o;
                o[0] = (_Float16)u.x;  o[1] = (_Float16)u.y;
                o[2] = (_Float16)u.z;  o[3] = (_Float16)u.w;
                o[4] = (_Float16)u2.x; o[5] = (_Float16)u2.y;
                o[6] = (_Float16)u2.z; o[7] = (_Float16)u2.w;
                *(f16x8*)&xls[sc][shalf * 32 + j * 8] = o;
            }
        }
        __syncthreads();
#pragma unroll
        for (int s = 0; s < 2; ++s) {
            int koff  = s * 32 + g * 8;       // px within chunk (B k-index)
            int ko128 = ch * 64 + koff;       // px within window (A k-index)
            f16x8 A0 = *(const f16x8*)&ebuf [r16][ko128];
            f16x8 A1 = *(const f16x8*)&wtbuf[r16][ko128];
            f16x8 B0 = *(const f16x8*)&xls[n0 + r16     ][koff];
            f16x8 B1 = *(const f16x8*)&xls[n0 + 16 + r16][koff];
            acc00 = __builtin_amdgcn_mfma_f32_16x16x32_f16(A0, B0, acc00, 0, 0, 0);
            acc01 = __builtin_amdgcn_mfma_f32_16x16x32_f16(A0, B1, acc01, 0, 0, 0);
            acc10 = __builtin_amdgcn_mfma_f32_16x16x32_f16(A1, B0, acc10, 0, 0, 0);
            acc11 = __builtin_amdgcn_mfma_f32_16x16x32_f16(A1, B1, acc11, 0, 0, 0);
        }
    }

    // ---- tail: write U (unnorm) and T tiles. D: row = g*4+reg, col = n0(+16)+r16 ----
    float* mp = Mpart + (size_t)(b * 32 + s5) * 8192;
    int colA = n0 + r16, colB = n0 + 16 + r16;
    int row0 = g * 4;
#pragma unroll
    for (int rr = 0; rr < 4; ++rr) {
        mp[(row0 + rr) * 256 + colA]        = acc00[rr];   // U
        mp[(row0 + rr) * 256 + colB]        = acc01[rr];
        mp[4096 + (row0 + rr) * 256 + colA] = acc10[rr];   // T
        mp[4096 + (row0 + rr) * 256 + colB] = acc11[rr];
    }
}

// ---- fused lambda + out (round-7 structure + 1/S scaling of U rows). ----
__global__ __launch_bounds__(256) void out_kernel(
    const float* __restrict__ qbn, const float* __restrict__ Mpart,
    const float* __restrict__ S, const float* __restrict__ vw,
    float* __restrict__ out)
{
    __shared__ float vls[64][260];
    __shared__ float msum[4][256];
    __shared__ float lam_s[4][64];
    __shared__ float sinv[4];
    int t = threadIdx.x;
    int b = blockIdx.x >> 4, s = blockIdx.x & 15;
    int h = s >> 2, qc = s & 3;

    if (t < 4) sinv[t] = 1.f / S[b * 16 + h * 4 + t];
    {   // stage vw[h]: 64 v x 256 c, coalesced float4
        const float* vwh = vw + (size_t)h * 64 * 256;
#pragma unroll
        for (int i = 0; i < 16; ++i) {
            int e = t + i * 256;
            int vv = e >> 6, c4 = (e & 63) * 4;
            *(float4*)&vls[vv][c4] = *(const float4*)(vwh + (size_t)vv * 256 + c4);
        }
    }
    __syncthreads();
    {   // msum[rr][c] = sinv[rr] * sum_s5 U + sum_s5 T   (coalesced, c = t)
        const float* mp = Mpart + (size_t)b * 32 * 8192 + t;
#pragma unroll
        for (int rr = 0; rr < 4; ++rr) {
            const float* mu = mp + (h * 4 + rr) * 256;
            float su = 0.f, st2 = 0.f;
            for (int s5 = 0; s5 < 32; ++s5) {
                su  += mu[s5 * 8192];
                st2 += mu[s5 * 8192 + 4096];
            }
            msum[rr][t] = su * sinv[rr] + st2;
        }
    }
    __syncthreads();
    {   // lam_s[rr][v] = sum_c msum[rr][c] * vls[v][c]
        int rr = t >> 6, v = t & 63;
        float acc = 0.f;
#pragma unroll 8
        for (int c4 = 0; c4 < 64; ++c4) {
            float4 a = *(const float4*)&vls[v][c4 * 4];
            float4 m = *(const float4*)&msum[rr][c4 * 4];
            acc += a.x*m.x + a.y*m.y + a.z*m.z + a.w*m.w;
        }
        lam_s[rr][v] = acc;
    }
    __syncthreads();

    int xy = qc * 1024 + t * 4;
    float4 q0 = *(const float4*)(qbn + ((size_t)b * 16 + h * 4 + 0) * WH + xy);
    float4 q1 = *(const float4*)(qbn + ((size_t)b * 16 + h * 4 + 1) * WH + xy);
    float4 q2 = *(const float4*)(qbn + ((size_t)b * 16 + h * 4 + 2) * WH + xy);
    float4 q3 = *(const float4*)(qbn + ((size_t)b * 16 + h * 4 + 3) * WH + xy);
    float* ob = out + ((size_t)b * 256 + (size_t)h * 64) * WH + xy;
#pragma unroll 8
    for (int v = 0; v < 64; ++v) {
        float l0 = lam_s[0][v], l1 = lam_s[1][v], l2 = lam_s[2][v], l3 = lam_s[3][v];
        float4 o;
        o.x = q0.x*l0 + q1.x*l1 + q2.x*l2 + q3.x*l3;
        o.y = q0.y*l0 + q1.y*l1 + q2.y*l2 + q3.y*l3;
        o.z = q0.z*l0 + q1.z*l1 + q2.z*l2 + q3.z*l3;
        o.w = q0.w*l0 + q1.w*l1 + q2.w*l2 + q3.w*l3;
        *(float4*)(ob + (size_t)v * WH) = o;
    }
}

extern "C" void kernel_launch(void* const* d_in, const int* in_sizes, int n_in,
                              void* d_out, int out_size, void* d_ws, size_t ws_size,
                              hipStream_t stream)
{
    const float* x   = (const float*)d_in[0];
    const float* qw  = (const float*)d_in[1];
    const float* qg  = (const float*)d_in[2];
    const float* qb  = (const float*)d_in[3];
    const float* qm  = (const float*)d_in[4];
    const float* qv  = (const float*)d_in[5];
    const float* kw  = (const float*)d_in[6];
    const float* kg  = (const float*)d_in[7];
    const float* kb  = (const float*)d_in[8];
    const float* km  = (const float*)d_in[9];
    const float* kv  = (const float*)d_in[10];
    const float* vw  = (const float*)d_in[11];
    const float* emb = (const float*)d_in[12];

    float* ws    = (float*)d_ws;
    float* qbn   = ws;
    float* Sv    = ws + 1048576;
    float* Wt    = ws + 1048832;
    float* Mpart = ws + 1114368;
    float* out   = (float*)d_out;

    hipLaunchKernelGGL(wt_kernel,   dim3(64),  dim3(256), 0, stream, emb, Wt, Sv);
    hipLaunchKernelGGL(main_kernel, dim3(512), dim3(512), 0, stream,
                       x, qw, kw, qg, qb, qm, qv, kg, kb, km, kv, Wt,
                       qbn, Sv, Mpart);
    hipLaunchKernelGGL(out_kernel,  dim3(256), dim3(256), 0, stream,
                       qbn, Mpart, Sv, vw, out);
}

// Round 9
// 105.079 us; speedup vs baseline: 1.1566x; 1.1566x over previous
//
#include <hip/hip_runtime.h>
#include <math.h>

#define C_   256
#define WH   4096

typedef _Float16 f16x8 __attribute__((ext_vector_type(8)));
typedef float    f32x4 __attribute__((ext_vector_type(4)));

// ---------------- workspace layout (floats) ----------------
// qbn   : [16][16][4096]           @ 0          (1,048,576)
// ebn   : [16][16][4096]           @ 1,048,576  (1,048,576)   exp(kk), unnormalized
// S     : [256] (atomic Σexp)      @ 2,097,152  (256)
// Wt    : [16][4096]               @ 2,097,408  (65,536)
// Mpart : [16][32 s5][32][256]     @ 2,162,944  (4,194,304)   rows 0-15 U(norm), 16-31 T
// lam   : [16][16][64]             @ 6,357,248  (16,384)

// ---- q/k 1x1 projections + BN (blocks 0..255; round-0 proven structure:
// 1024 thr, q+k fused per thread, scalar x loads -> 1 MB/CU L1 traffic,
// 16 waves/CU) + exp(kk) unnormalized + S atomics. Wt gen (blocks 256..319). ----
__global__ __launch_bounds__(1024) void proj_kernel(
    const float* __restrict__ x,
    const float* __restrict__ qw, const float* __restrict__ kw,
    const float* __restrict__ qg, const float* __restrict__ qb,
    const float* __restrict__ qm, const float* __restrict__ qv,
    const float* __restrict__ kg, const float* __restrict__ kb,
    const float* __restrict__ km, const float* __restrict__ kv,
    const float* __restrict__ emb,
    float* __restrict__ qbn, float* __restrict__ ebn,
    float* __restrict__ S, float* __restrict__ Wt)
{
    if (blockIdx.x >= 256) {
        // ---- Wt: summed spatial weight of the positional conv ----
        int wb = blockIdx.x - 256;
        int hk = wb >> 2, quarter = wb & 3;
        int h = hk >> 2, k = hk & 3;
        const float* e = emb + (size_t)(k * 4 + h) * 529;   // emb[k][h][0][0][i][j]
        __shared__ float colsum[23][64];
        for (int t2 = threadIdx.x; t2 < 23 * 64; t2 += 1024) {
            int i = t2 / 64, q = t2 % 64;
            int jlo = max(0, q - 52), jhi = min(22, q + 11);
            float s = 0.f;
            for (int j = jlo; j <= jhi; ++j) s += e[i * 23 + j];
            colsum[i][q] = s;
        }
        __syncthreads();
        {
            int t2 = quarter * 1024 + threadIdx.x;
            int p = t2 >> 6, q = t2 & 63;
            int ilo = max(0, p - 52), ihi = min(22, p + 11);
            float s = 0.f;
            for (int i = ilo; i <= ihi; ++i) s += colsum[i][q];
            Wt[(size_t)hk * WH + t2] = s;
        }
        return;
    }

    int t = threadIdx.x;
    int b = blockIdx.x >> 4, chunk = blockIdx.x & 15;
    int px = t & 255;
    int lane = t & 63;
    int og = __builtin_amdgcn_readfirstlane(t >> 8);   // 0..3, wave-uniform
    int o4 = og * 4;
    int xy = chunk * 256 + px;

    const float* wq0 = qw + (size_t)(o4 + 0) * 256;
    const float* wq1 = qw + (size_t)(o4 + 1) * 256;
    const float* wq2 = qw + (size_t)(o4 + 2) * 256;
    const float* wq3 = qw + (size_t)(o4 + 3) * 256;
    const float* wk0 = kw + (size_t)(o4 + 0) * 256;
    const float* wk1 = kw + (size_t)(o4 + 1) * 256;
    const float* wk2 = kw + (size_t)(o4 + 2) * 256;
    const float* wk3 = kw + (size_t)(o4 + 3) * 256;

    float accq[4] = {0.f, 0.f, 0.f, 0.f};
    float acck[4] = {0.f, 0.f, 0.f, 0.f};
    const float* xb = x + (size_t)b * C_ * WH + xy;
#pragma unroll 8
    for (int c = 0; c < 256; ++c) {
        float xv = xb[(size_t)c * WH];
        accq[0] += xv * wq0[c]; accq[1] += xv * wq1[c];
        accq[2] += xv * wq2[c]; accq[3] += xv * wq3[c];
        acck[0] += xv * wk0[c]; acck[1] += xv * wk1[c];
        acck[2] += xv * wk2[c]; acck[3] += xv * wk3[c];
    }
#pragma unroll
    for (int i = 0; i < 4; ++i) {
        int hk = o4 + i;
        float s  = qg[hk] * rsqrtf(qv[hk] + 1e-5f);
        float tq = qb[hk] - qm[hk] * s;
        float s2 = kg[hk] * rsqrtf(kv[hk] + 1e-5f);
        float tk = kb[hk] - km[hk] * s2;
        qbn[((size_t)b * 16 + hk) * WH + xy] = accq[i] * s + tq;
        // unnormalized softmax numerator: |kk| is BN-bounded, exp safe (round-8 proof)
        float e = __expf(acck[i] * s2 + tk);
        ebn[((size_t)b * 16 + hk) * WH + xy] = e;
        float ssum = e;
#pragma unroll
        for (int off = 32; off; off >>= 1) ssum += __shfl_xor(ssum, off, 64);
        if (lane == 0) atomicAdd(&S[b * 16 + hk], ssum);
    }
}

// ---- U/T contractions via fp16 MFMA (fp32 accumulate). Round-5 proven body.
// Grid 512 = (b, s5 of 128 xy), 2 blocks/CU. W rows 0-15 = ebn * (1/S)
// (normalized sm; no expf here), rows 16-31 = Wt. ----
__global__ __launch_bounds__(512) void ut_kernel(
    const float* __restrict__ x, const float* __restrict__ ebn,
    const float* __restrict__ S, const float* __restrict__ Wt,
    float* __restrict__ Mpart)
{
    __shared__ _Float16 xls[256][72];   // 36,864 B : X rows (c), 64 k per chunk
    __shared__ _Float16 wls[32][72];    //  4,608 B : W rows (r), 64 k per chunk
    __shared__ float st[16];            // 1/S per sm row
    int t = threadIdx.x;
    int b = blockIdx.x >> 5, s5 = blockIdx.x & 31;
    int xys0 = s5 * 128;
    int lane = t & 63;
    int wid = __builtin_amdgcn_readfirstlane(t >> 6);   // 0..7
    int r16 = lane & 15, g = lane >> 4;
    int n0 = wid * 32;

    if (t < 16) st[t] = 1.f / S[b * 16 + t];

    // staging coords
    int sc = t >> 1, shalf = t & 1;                 // x: row sc, 32-col half
    int wr = t >> 3, wco = (t & 7) * 8;             // w: row wr (t<256 only)

    f32x4 acc00 = {0.f,0.f,0.f,0.f}, acc01 = {0.f,0.f,0.f,0.f};
    f32x4 acc10 = {0.f,0.f,0.f,0.f}, acc11 = {0.f,0.f,0.f,0.f};

    for (int ch = 0; ch < 2; ++ch) {
        int kbase = xys0 + ch * 64;
        __syncthreads();                            // st[] visible / prev reads done
        {   // stage X: 256 rows x 64 k  (thread: row sc, cols shalf*32..+31)
            const float* xp = x + ((size_t)b * C_ + sc) * WH + kbase + shalf * 32;
#pragma unroll
            for (int j = 0; j < 4; ++j) {
                float4 u  = *(const float4*)(xp + j * 8);
                float4 u2 = *(const float4*)(xp + j * 8 + 4);
                f16x8 o;
                o[0] = (_Float16)u.x;  o[1] = (_Float16)u.y;
                o[2] = (_Float16)u.z;  o[3] = (_Float16)u.w;
                o[4] = (_Float16)u2.x; o[5] = (_Float16)u2.y;
                o[6] = (_Float16)u2.z; o[7] = (_Float16)u2.w;
                *(f16x8*)&xls[sc][shalf * 32 + j * 8] = o;
            }
        }
        if (t < 256) {  // stage W: rows 0..15 = ebn*(1/S), 16..31 = Wt
            const float* src = (wr < 16)
                ? ebn + ((size_t)b * 16 + wr) * WH + kbase + wco
                : Wt + (size_t)(wr - 16) * WH + kbase + wco;
            float scale = (wr < 16) ? st[wr] : 1.f;
            float4 u  = *(const float4*)(src);
            float4 u2 = *(const float4*)(src + 4);
            f16x8 o;
            o[0] = (_Float16)(u.x  * scale); o[1] = (_Float16)(u.y  * scale);
            o[2] = (_Float16)(u.z  * scale); o[3] = (_Float16)(u.w  * scale);
            o[4] = (_Float16)(u2.x * scale); o[5] = (_Float16)(u2.y * scale);
            o[6] = (_Float16)(u2.z * scale); o[7] = (_Float16)(u2.w * scale);
            *(f16x8*)&wls[wr][wco] = o;
        }
        __syncthreads();                            // tile visible
#pragma unroll
        for (int s = 0; s < 2; ++s) {
            int koff = s * 32 + g * 8;
            f16x8 A0 = *(const f16x8*)&wls[r16     ][koff];
            f16x8 A1 = *(const f16x8*)&wls[16 + r16][koff];
            f16x8 B0 = *(const f16x8*)&xls[n0 + r16     ][koff];
            f16x8 B1 = *(const f16x8*)&xls[n0 + 16 + r16][koff];
            acc00 = __builtin_amdgcn_mfma_f32_16x16x32_f16(A0, B0, acc00, 0, 0, 0);
            acc01 = __builtin_amdgcn_mfma_f32_16x16x32_f16(A0, B1, acc01, 0, 0, 0);
            acc10 = __builtin_amdgcn_mfma_f32_16x16x32_f16(A1, B0, acc10, 0, 0, 0);
            acc11 = __builtin_amdgcn_mfma_f32_16x16x32_f16(A1, B1, acc11, 0, 0, 0);
        }
    }

    // D layout: row = mt*16 + g*4 + reg, col = n0 + nt*16 + r16
    float* mp = Mpart + (size_t)(b * 32 + s5) * 8192;
    int colA = n0 + r16, colB = n0 + 16 + r16;
    int row0 = g * 4, row1 = 16 + g * 4;
#pragma unroll
    for (int rr = 0; rr < 4; ++rr) {
        mp[(row0 + rr) * 256 + colA] = acc00[rr];
        mp[(row0 + rr) * 256 + colB] = acc01[rr];
        mp[(row1 + rr) * 256 + colA] = acc10[rr];
        mp[(row1 + rr) * 256 + colB] = acc11[rr];
    }
}

// ---- lambda[b,hk,v] = sum_c v_w[h,v,c] * (U+T)[b,hk,c]. One block per (b,hk). ----
__global__ __launch_bounds__(256) void lam_kernel(
    const float* __restrict__ Mpart, const float* __restrict__ vw,
    float* __restrict__ lam)
{
    __shared__ float msum[256];
    __shared__ float vls[64][68];
    __shared__ float psum[4][64];
    int t = threadIdx.x;
    int b = blockIdx.x >> 4, hk = blockIdx.x & 15, h = hk >> 2;

    {
        const float* mp = Mpart + (size_t)b * 32 * 8192 + t;
        float s = 0.f;
        for (int seg = 0; seg < 32; ++seg) {
            const float* m2 = mp + (size_t)seg * 8192;
            s += m2[hk * 256] + m2[(16 + hk) * 256];
        }
        msum[t] = s;
    }

    int v = t & 63, cq = t >> 6;
    float acc = 0.f;
    const float* vwh = vw + (size_t)h * 64 * 256;
    for (int ch = 0; ch < 4; ++ch) {
        __syncthreads();
#pragma unroll
        for (int k = 0; k < 4; ++k) {
            int e = t + k * 256;
            int vv = e >> 4, c4 = (e & 15) * 4;
            *(float4*)&vls[vv][c4] = *(const float4*)(vwh + (size_t)vv * 256 + ch * 64 + c4);
        }
        __syncthreads();
#pragma unroll
        for (int i4 = 0; i4 < 4; ++i4) {
            float4 a  = *(const float4*)&vls[v][cq * 16 + i4 * 4];
            float4 m4 = *(const float4*)&msum[ch * 64 + cq * 16 + i4 * 4];
            acc += a.x * m4.x + a.y * m4.y + a.z * m4.z + a.w * m4.w;
        }
    }
    psum[cq][v] = acc;
    __syncthreads();
    if (t < 64)
        lam[((size_t)b * 16 + hk) * 64 + t] =
            psum[0][t] + psum[1][t] + psum[2][t] + psum[3][t];
}

// ---- out[b, h*64+v, xy] = sum_k qbn[b,hk,xy] * lam[b,hk,v]. ----
__global__ __launch_bounds__(256) void out_kernel(
    const float* __restrict__ qbn, const float* __restrict__ lam,
    float* __restrict__ out)
{
    int t = threadIdx.x;
    int b = blockIdx.x >> 4, s = blockIdx.x & 15;
    int h = s >> 2, qc = s & 3;
    int xy = qc * 1024 + t * 4;
    float4 q0 = *(const float4*)(qbn + ((size_t)b * 16 + h * 4 + 0) * WH + xy);
    float4 q1 = *(const float4*)(qbn + ((size_t)b * 16 + h * 4 + 1) * WH + xy);
    float4 q2 = *(const float4*)(qbn + ((size_t)b * 16 + h * 4 + 2) * WH + xy);
    float4 q3 = *(const float4*)(qbn + ((size_t)b * 16 + h * 4 + 3) * WH + xy);
    const float* lb = lam + (size_t)b * 1024 + (size_t)h * 256;
    float* ob = out + ((size_t)b * 256 + (size_t)h * 64) * WH + xy;
#pragma unroll 8
    for (int v = 0; v < 64; ++v) {
        float l0 = lb[v], l1 = lb[64 + v], l2 = lb[128 + v], l3 = lb[192 + v];
        float4 o;
        o.x = q0.x*l0 + q1.x*l1 + q2.x*l2 + q3.x*l3;
        o.y = q0.y*l0 + q1.y*l1 + q2.y*l2 + q3.y*l3;
        o.z = q0.z*l0 + q1.z*l1 + q2.z*l2 + q3.z*l3;
        o.w = q0.w*l0 + q1.w*l1 + q2.w*l2 + q3.w*l3;
        *(float4*)(ob + (size_t)v * WH) = o;
    }
}

extern "C" void kernel_launch(void* const* d_in, const int* in_sizes, int n_in,
                              void* d_out, int out_size, void* d_ws, size_t ws_size,
                              hipStream_t stream)
{
    const float* x   = (const float*)d_in[0];
    const float* qw  = (const float*)d_in[1];
    const float* qg  = (const float*)d_in[2];
    const float* qb  = (const float*)d_in[3];
    const float* qm  = (const float*)d_in[4];
    const float* qv  = (const float*)d_in[5];
    const float* kw  = (const float*)d_in[6];
    const float* kg  = (const float*)d_in[7];
    const float* kb  = (const float*)d_in[8];
    const float* km  = (const float*)d_in[9];
    const float* kv  = (const float*)d_in[10];
    const float* vw  = (const float*)d_in[11];
    const float* emb = (const float*)d_in[12];

    float* ws    = (float*)d_ws;
    float* qbn   = ws;
    float* ebn   = ws + 1048576;
    float* Sv    = ws + 2097152;
    float* Wt    = ws + 2097408;
    float* Mpart = ws + 2162944;
    float* lam   = ws + 6357248;
    float* out   = (float*)d_out;

    hipMemsetAsync(Sv, 0, 256 * sizeof(float), stream);
    hipLaunchKernelGGL(proj_kernel,  dim3(320), dim3(1024), 0, stream,
                       x, qw, kw, qg, qb, qm, qv, kg, kb, km, kv, emb,
                       qbn, ebn, Sv, Wt);
    hipLaunchKernelGGL(ut_kernel,    dim3(512), dim3(512), 0, stream,
                       x, ebn, Sv, Wt, Mpart);
    hipLaunchKernelGGL(lam_kernel,   dim3(256), dim3(256), 0, stream, Mpart, vw, lam);
    hipLaunchKernelGGL(out_kernel,   dim3(256), dim3(256), 0, stream, qbn, lam, out);
}

// Round 10
// 84.338 us; speedup vs baseline: 1.4411x; 1.2459x over previous
//
#include <hip/hip_runtime.h>
#include <math.h>

#define C_   256
#define WH   4096

typedef _Float16 f16x8 __attribute__((ext_vector_type(8)));
typedef float    f32x4 __attribute__((ext_vector_type(4)));

// ---------------- workspace layout (floats) ----------------
// qbn   : [16][16][4096]           @ 0          (1,048,576)
// ebn   : [16][16][4096]           @ 1,048,576  (1,048,576)   exp(kk), unnormalized
// S     : [256] (atomic Σexp)      @ 2,097,152  (256)
// Wt    : [16][4096]               @ 2,097,408  (65,536)
// Mpart : [16][32 s5][32][256]     @ 2,162,944  (4,194,304)   rows 0-15 U(norm), 16-31 T
// lam   : [16][16][64]             @ 6,357,248  (16,384)

// ---- q/k 1x1 projections + BN + exp(kk) + S atomics (blocks 0..255)
//      + Wt generation (blocks 256..319).
// Proj tiling: 8 waves = 4 row-groups x 2 c-halves. Each wave: 8 rows x 128 c
// (float4 x loads -> 1 MB/CU L1, half of round-5's 2 MB). c-halves merged via
// LDS part[32][256]; epilogue (BN, exp, S-reduce) on the chalf=1 waves. ----
__global__ __launch_bounds__(512) void proj_kernel(
    const float* __restrict__ x,
    const float* __restrict__ qw, const float* __restrict__ kw,
    const float* __restrict__ qg, const float* __restrict__ qb,
    const float* __restrict__ qm, const float* __restrict__ qv,
    const float* __restrict__ kg, const float* __restrict__ kb,
    const float* __restrict__ km, const float* __restrict__ kv,
    const float* __restrict__ emb,
    float* __restrict__ qbn, float* __restrict__ ebn,
    float* __restrict__ S, float* __restrict__ Wt)
{
    if (blockIdx.x >= 256) {
        // ---- Wt: summed spatial weight of the positional conv (round-7 code) ----
        int wb = blockIdx.x - 256;
        int hk = wb >> 2, quarter = wb & 3;
        int h = hk >> 2, k = hk & 3;
        const float* e = emb + (size_t)(k * 4 + h) * 529;   // emb[k][h][0][0][i][j]
        __shared__ float colsum[23][64];
        for (int t2 = threadIdx.x; t2 < 23 * 64; t2 += 512) {
            int i = t2 / 64, q = t2 % 64;
            int jlo = max(0, q - 52), jhi = min(22, q + 11);
            float s = 0.f;
            for (int j = jlo; j <= jhi; ++j) s += e[i * 23 + j];
            colsum[i][q] = s;
        }
        __syncthreads();
        for (int tt = threadIdx.x; tt < 1024; tt += 512) {
            int t2 = quarter * 1024 + tt;
            int p = t2 >> 6, q = t2 & 63;
            int ilo = max(0, p - 52), ihi = min(22, p + 11);
            float s = 0.f;
            for (int i = ilo; i <= ihi; ++i) s += colsum[i][q];
            Wt[(size_t)hk * WH + t2] = s;
        }
        return;
    }

    __shared__ float part[32][256];    // 32,768 B : chalf-0 partial sums
    int t = threadIdx.x, lane = t & 63;
    int w = __builtin_amdgcn_readfirstlane(t >> 6);   // 0..7, wave-uniform
    int b = blockIdx.x >> 4, chunk = blockIdx.x & 15;
    int xy = chunk * 256 + lane * 4;
    int rg = w & 3;                 // row group: rows rg*8 .. rg*8+8
    int chalf = w >> 2;             // c half: [0,128) or [128,256)
    int isK = rg >> 1;              // rg 0,1 -> q rows 0-15; rg 2,3 -> k rows 0-15
    int r0 = (rg & 1) * 8;          // hk base within q or k

    const float* wsrc = isK ? kw : qw;
    const float* w0 = wsrc + (size_t)(r0 + 0) * 256 + chalf * 128;
    const float* w1 = wsrc + (size_t)(r0 + 1) * 256 + chalf * 128;
    const float* w2 = wsrc + (size_t)(r0 + 2) * 256 + chalf * 128;
    const float* w3 = wsrc + (size_t)(r0 + 3) * 256 + chalf * 128;
    const float* w4 = wsrc + (size_t)(r0 + 4) * 256 + chalf * 128;
    const float* w5 = wsrc + (size_t)(r0 + 5) * 256 + chalf * 128;
    const float* w6 = wsrc + (size_t)(r0 + 6) * 256 + chalf * 128;
    const float* w7 = wsrc + (size_t)(r0 + 7) * 256 + chalf * 128;

    float4 a0 = {0,0,0,0}, a1 = {0,0,0,0}, a2 = {0,0,0,0}, a3 = {0,0,0,0};
    float4 a4 = {0,0,0,0}, a5 = {0,0,0,0}, a6 = {0,0,0,0}, a7 = {0,0,0,0};
    const float* xb = x + ((size_t)b * C_ + chalf * 128) * WH + xy;
#pragma unroll 8
    for (int c = 0; c < 128; ++c) {
        float4 xv = *(const float4*)(xb + (size_t)c * WH);
        float f0 = w0[c], f1 = w1[c], f2 = w2[c], f3 = w3[c];
        float f4 = w4[c], f5 = w5[c], f6 = w6[c], f7 = w7[c];
        a0.x += xv.x*f0; a0.y += xv.y*f0; a0.z += xv.z*f0; a0.w += xv.w*f0;
        a1.x += xv.x*f1; a1.y += xv.y*f1; a1.z += xv.z*f1; a1.w += xv.w*f1;
        a2.x += xv.x*f2; a2.y += xv.y*f2; a2.z += xv.z*f2; a2.w += xv.w*f2;
        a3.x += xv.x*f3; a3.y += xv.y*f3; a3.z += xv.z*f3; a3.w += xv.w*f3;
        a4.x += xv.x*f4; a4.y += xv.y*f4; a4.z += xv.z*f4; a4.w += xv.w*f4;
        a5.x += xv.x*f5; a5.y += xv.y*f5; a5.z += xv.z*f5; a5.w += xv.w*f5;
        a6.x += xv.x*f6; a6.y += xv.y*f6; a6.z += xv.z*f6; a6.w += xv.w*f6;
        a7.x += xv.x*f7; a7.y += xv.y*f7; a7.z += xv.z*f7; a7.w += xv.w*f7;
    }
    float4 acc[8] = {a0, a1, a2, a3, a4, a5, a6, a7};

    int rbase = rg * 8;
    if (chalf == 0) {
#pragma unroll
        for (int i = 0; i < 8; ++i)
            *(float4*)&part[rbase + i][lane * 4] = acc[i];
    }
    __syncthreads();
    if (chalf == 1) {
#pragma unroll
        for (int i = 0; i < 8; ++i) {
            float4 p = *(const float4*)&part[rbase + i][lane * 4];
            acc[i].x += p.x; acc[i].y += p.y; acc[i].z += p.z; acc[i].w += p.w;
        }
        if (!isK) {
#pragma unroll
            for (int i = 0; i < 8; ++i) {
                int hk = r0 + i;
                float s  = qg[hk] * rsqrtf(qv[hk] + 1e-5f);
                float tq = qb[hk] - qm[hk] * s;
                float4 o;
                o.x = acc[i].x * s + tq; o.y = acc[i].y * s + tq;
                o.z = acc[i].z * s + tq; o.w = acc[i].w * s + tq;
                *(float4*)(qbn + ((size_t)b * 16 + hk) * WH + xy) = o;
            }
        } else {
#pragma unroll
            for (int i = 0; i < 8; ++i) {
                int hk = r0 + i;
                float s2 = kg[hk] * rsqrtf(kv[hk] + 1e-5f);
                float tk = kb[hk] - km[hk] * s2;
                float4 o;
                o.x = __expf(acc[i].x * s2 + tk);
                o.y = __expf(acc[i].y * s2 + tk);
                o.z = __expf(acc[i].z * s2 + tk);
                o.w = __expf(acc[i].w * s2 + tk);
                *(float4*)(ebn + ((size_t)b * 16 + hk) * WH + xy) = o;
                float ssum = o.x + o.y + o.z + o.w;
#pragma unroll
                for (int off = 32; off; off >>= 1) ssum += __shfl_xor(ssum, off, 64);
                if (lane == 0) atomicAdd(&S[b * 16 + hk], ssum);
            }
        }
    }
}

// ---- U/T contractions via fp16 MFMA (fp32 accumulate). Round-5/9 proven body.
// Grid 512 = (b, s5 of 128 xy), 2 blocks/CU. W rows 0-15 = ebn * (1/S),
// rows 16-31 = Wt. ----
__global__ __launch_bounds__(512) void ut_kernel(
    const float* __restrict__ x, const float* __restrict__ ebn,
    const float* __restrict__ S, const float* __restrict__ Wt,
    float* __restrict__ Mpart)
{
    __shared__ _Float16 xls[256][72];   // 36,864 B : X rows (c), 64 k per chunk
    __shared__ _Float16 wls[32][72];    //  4,608 B : W rows (r), 64 k per chunk
    __shared__ float st[16];            // 1/S per sm row
    int t = threadIdx.x;
    int b = blockIdx.x >> 5, s5 = blockIdx.x & 31;
    int xys0 = s5 * 128;
    int lane = t & 63;
    int wid = __builtin_amdgcn_readfirstlane(t >> 6);   // 0..7
    int r16 = lane & 15, g = lane >> 4;
    int n0 = wid * 32;

    if (t < 16) st[t] = 1.f / S[b * 16 + t];

    // staging coords
    int sc = t >> 1, shalf = t & 1;                 // x: row sc, 32-col half
    int wr = t >> 3, wco = (t & 7) * 8;             // w: row wr (t<256 only)

    f32x4 acc00 = {0.f,0.f,0.f,0.f}, acc01 = {0.f,0.f,0.f,0.f};
    f32x4 acc10 = {0.f,0.f,0.f,0.f}, acc11 = {0.f,0.f,0.f,0.f};

    for (int ch = 0; ch < 2; ++ch) {
        int kbase = xys0 + ch * 64;
        __syncthreads();                            // st[] visible / prev reads done
        {   // stage X: 256 rows x 64 k  (thread: row sc, cols shalf*32..+31)
            const float* xp = x + ((size_t)b * C_ + sc) * WH + kbase + shalf * 32;
#pragma unroll
            for (int j = 0; j < 4; ++j) {
                float4 u  = *(const float4*)(xp + j * 8);
                float4 u2 = *(const float4*)(xp + j * 8 + 4);
                f16x8 o;
                o[0] = (_Float16)u.x;  o[1] = (_Float16)u.y;
                o[2] = (_Float16)u.z;  o[3] = (_Float16)u.w;
                o[4] = (_Float16)u2.x; o[5] = (_Float16)u2.y;
                o[6] = (_Float16)u2.z; o[7] = (_Float16)u2.w;
                *(f16x8*)&xls[sc][shalf * 32 + j * 8] = o;
            }
        }
        if (t < 256) {  // stage W: rows 0..15 = ebn*(1/S), 16..31 = Wt
            const float* src = (wr < 16)
                ? ebn + ((size_t)b * 16 + wr) * WH + kbase + wco
                : Wt + (size_t)(wr - 16) * WH + kbase + wco;
            float scale = (wr < 16) ? st[wr] : 1.f;
            float4 u  = *(const float4*)(src);
            float4 u2 = *(const float4*)(src + 4);
            f16x8 o;
            o[0] = (_Float16)(u.x  * scale); o[1] = (_Float16)(u.y  * scale);
            o[2] = (_Float16)(u.z  * scale); o[3] = (_Float16)(u.w  * scale);
            o[4] = (_Float16)(u2.x * scale); o[5] = (_Float16)(u2.y * scale);
            o[6] = (_Float16)(u2.z * scale); o[7] = (_Float16)(u2.w * scale);
            *(f16x8*)&wls[wr][wco] = o;
        }
        __syncthreads();                            // tile visible
#pragma unroll
        for (int s = 0; s < 2; ++s) {
            int koff = s * 32 + g * 8;
            f16x8 A0 = *(const f16x8*)&wls[r16     ][koff];
            f16x8 A1 = *(const f16x8*)&wls[16 + r16][koff];
            f16x8 B0 = *(const f16x8*)&xls[n0 + r16     ][koff];
            f16x8 B1 = *(const f16x8*)&xls[n0 + 16 + r16][koff];
            acc00 = __builtin_amdgcn_mfma_f32_16x16x32_f16(A0, B0, acc00, 0, 0, 0);
            acc01 = __builtin_amdgcn_mfma_f32_16x16x32_f16(A0, B1, acc01, 0, 0, 0);
            acc10 = __builtin_amdgcn_mfma_f32_16x16x32_f16(A1, B0, acc10, 0, 0, 0);
            acc11 = __builtin_amdgcn_mfma_f32_16x16x32_f16(A1, B1, acc11, 0, 0, 0);
        }
    }

    // D layout: row = mt*16 + g*4 + reg, col = n0 + nt*16 + r16
    float* mp = Mpart + (size_t)(b * 32 + s5) * 8192;
    int colA = n0 + r16, colB = n0 + 16 + r16;
    int row0 = g * 4, row1 = 16 + g * 4;
#pragma unroll
    for (int rr = 0; rr < 4; ++rr) {
        mp[(row0 + rr) * 256 + colA] = acc00[rr];
        mp[(row0 + rr) * 256 + colB] = acc01[rr];
        mp[(row1 + rr) * 256 + colA] = acc10[rr];
        mp[(row1 + rr) * 256 + colB] = acc11[rr];
    }
}

// ---- lambda[b,hk,v] = sum_c v_w[h,v,c] * (U+T)[b,hk,c]. One block per (b,hk). ----
__global__ __launch_bounds__(256) void lam_kernel(
    const float* __restrict__ Mpart, const float* __restrict__ vw,
    float* __restrict__ lam)
{
    __shared__ float msum[256];
    __shared__ float vls[64][68];
    __shared__ float psum[4][64];
    int t = threadIdx.x;
    int b = blockIdx.x >> 4, hk = blockIdx.x & 15, h = hk >> 2;

    {
        const float* mp = Mpart + (size_t)b * 32 * 8192 + t;
        float s = 0.f;
        for (int seg = 0; seg < 32; ++seg) {
            const float* m2 = mp + (size_t)seg * 8192;
            s += m2[hk * 256] + m2[(16 + hk) * 256];
        }
        msum[t] = s;
    }

    int v = t & 63, cq = t >> 6;
    float acc = 0.f;
    const float* vwh = vw + (size_t)h * 64 * 256;
    for (int ch = 0; ch < 4; ++ch) {
        __syncthreads();
#pragma unroll
        for (int k = 0; k < 4; ++k) {
            int e = t + k * 256;
            int vv = e >> 4, c4 = (e & 15) * 4;
            *(float4*)&vls[vv][c4] = *(const float4*)(vwh + (size_t)vv * 256 + ch * 64 + c4);
        }
        __syncthreads();
#pragma unroll
        for (int i4 = 0; i4 < 4; ++i4) {
            float4 a  = *(const float4*)&vls[v][cq * 16 + i4 * 4];
            float4 m4 = *(const float4*)&msum[ch * 64 + cq * 16 + i4 * 4];
            acc += a.x * m4.x + a.y * m4.y + a.z * m4.z + a.w * m4.w;
        }
    }
    psum[cq][v] = acc;
    __syncthreads();
    if (t < 64)
        lam[((size_t)b * 16 + hk) * 64 + t] =
            psum[0][t] + psum[1][t] + psum[2][t] + psum[3][t];
}

// ---- out[b, h*64+v, xy] = sum_k qbn[b,hk,xy] * lam[b,hk,v]. ----
__global__ __launch_bounds__(256) void out_kernel(
    const float* __restrict__ qbn, const float* __restrict__ lam,
    float* __restrict__ out)
{
    int t = threadIdx.x;
    int b = blockIdx.x >> 4, s = blockIdx.x & 15;
    int h = s >> 2, qc = s & 3;
    int xy = qc * 1024 + t * 4;
    float4 q0 = *(const float4*)(qbn + ((size_t)b * 16 + h * 4 + 0) * WH + xy);
    float4 q1 = *(const float4*)(qbn + ((size_t)b * 16 + h * 4 + 1) * WH + xy);
    float4 q2 = *(const float4*)(qbn + ((size_t)b * 16 + h * 4 + 2) * WH + xy);
    float4 q3 = *(const float4*)(qbn + ((size_t)b * 16 + h * 4 + 3) * WH + xy);
    const float* lb = lam + (size_t)b * 1024 + (size_t)h * 256;
    float* ob = out + ((size_t)b * 256 + (size_t)h * 64) * WH + xy;
#pragma unroll 8
    for (int v = 0; v < 64; ++v) {
        float l0 = lb[v], l1 = lb[64 + v], l2 = lb[128 + v], l3 = lb[192 + v];
        float4 o;
        o.x = q0.x*l0 + q1.x*l1 + q2.x*l2 + q3.x*l3;
        o.y = q0.y*l0 + q1.y*l1 + q2.y*l2 + q3.y*l3;
        o.z = q0.z*l0 + q1.z*l1 + q2.z*l2 + q3.z*l3;
        o.w = q0.w*l0 + q1.w*l1 + q2.w*l2 + q3.w*l3;
        *(float4*)(ob + (size_t)v * WH) = o;
    }
}

extern "C" void kernel_launch(void* const* d_in, const int* in_sizes, int n_in,
                              void* d_out, int out_size, void* d_ws, size_t ws_size,
                              hipStream_t stream)
{
    const float* x   = (const float*)d_in[0];
    const float* qw  = (const float*)d_in[1];
    const float* qg  = (const float*)d_in[2];
    const float* qb  = (const float*)d_in[3];
    const float* qm  = (const float*)d_in[4];
    const float* qv  = (const float*)d_in[5];
    const float* kw  = (const float*)d_in[6];
    const float* kg  = (const float*)d_in[7];
    const float* kb  = (const float*)d_in[8];
    const float* km  = (const float*)d_in[9];
    const float* kv  = (const float*)d_in[10];
    const float* vw  = (const float*)d_in[11];
    const float* emb = (const float*)d_in[12];

    float* ws    = (float*)d_ws;
    float* qbn   = ws;
    float* ebn   = ws + 1048576;
    float* Sv    = ws + 2097152;
    float* Wt    = ws + 2097408;
    float* Mpart = ws + 2162944;
    float* lam   = ws + 6357248;
    float* out   = (float*)d_out;

    hipMemsetAsync(Sv, 0, 256 * sizeof(float), stream);
    hipLaunchKernelGGL(proj_kernel,  dim3(320), dim3(512), 0, stream,
                       x, qw, kw, qg, qb, qm, qv, kg, kb, km, kv, emb,
                       qbn, ebn, Sv, Wt);
    hipLaunchKernelGGL(ut_kernel,    dim3(512), dim3(512), 0, stream,
                       x, ebn, Sv, Wt, Mpart);
    hipLaunchKernelGGL(lam_kernel,   dim3(256), dim3(256), 0, stream, Mpart, vw, lam);
    hipLaunchKernelGGL(out_kernel,   dim3(256), dim3(256), 0, stream, qbn, lam, out);
}

// Round 11
// 82.172 us; speedup vs baseline: 1.4790x; 1.0264x over previous
//
#include <hip/hip_runtime.h>
#include <math.h>

#define C_   256
#define WH   4096

typedef _Float16 f16x8 __attribute__((ext_vector_type(8)));
typedef float    f32x4 __attribute__((ext_vector_type(4)));

// ---------------- workspace layout (floats) ----------------
// qbn   : [16][16][4096]           @ 0          (1,048,576)
// ebn   : [16][16][4096]           @ 1,048,576  (1,048,576)   exp(kk), unnormalized
// S     : [256] (atomic Σexp)      @ 2,097,152  (256)
// Wt    : [16][4096]               @ 2,097,408  (65,536)
// Mpart : [16][32 s5][16][256]     @ 2,162,944  (2,097,152)   merged U(norm)+T
// lam   : [16][16][64]             @ 4,260,096  (16,384)

// ---- q/k 1x1 projections + BN (blocks 0..255; ROUND-5 PROVEN STRUCTURE:
// 8 waves x 4 rows, full 256-c, float4 x loads) + exp(kk) + S atomics
// + Wt generation (blocks 256..319). ----
__global__ __launch_bounds__(512) void proj_kernel(
    const float* __restrict__ x,
    const float* __restrict__ qw, const float* __restrict__ kw,
    const float* __restrict__ qg, const float* __restrict__ qb,
    const float* __restrict__ qm, const float* __restrict__ qv,
    const float* __restrict__ kg, const float* __restrict__ kb,
    const float* __restrict__ km, const float* __restrict__ kv,
    const float* __restrict__ emb,
    float* __restrict__ qbn, float* __restrict__ ebn,
    float* __restrict__ S, float* __restrict__ Wt)
{
    if (blockIdx.x >= 256) {
        // ---- Wt: summed spatial weight of the positional conv ----
        int wb = blockIdx.x - 256;
        int hk = wb >> 2, quarter = wb & 3;
        int h = hk >> 2, k = hk & 3;
        const float* e = emb + (size_t)(k * 4 + h) * 529;   // emb[k][h][0][0][i][j]
        __shared__ float colsum[23][64];
        for (int t2 = threadIdx.x; t2 < 23 * 64; t2 += 512) {
            int i = t2 / 64, q = t2 % 64;
            int jlo = max(0, q - 52), jhi = min(22, q + 11);
            float s = 0.f;
            for (int j = jlo; j <= jhi; ++j) s += e[i * 23 + j];
            colsum[i][q] = s;
        }
        __syncthreads();
        for (int tt = threadIdx.x; tt < 1024; tt += 512) {
            int t2 = quarter * 1024 + tt;
            int p = t2 >> 6, q = t2 & 63;
            int ilo = max(0, p - 52), ihi = min(22, p + 11);
            float s = 0.f;
            for (int i = ilo; i <= ihi; ++i) s += colsum[i][q];
            Wt[(size_t)hk * WH + t2] = s;
        }
        return;
    }

    int t = threadIdx.x;
    int b = blockIdx.x >> 4, chunk = blockIdx.x & 15;
    int lane = t & 63;
    int og = __builtin_amdgcn_readfirstlane(t >> 6);   // 0..7, wave-uniform
    int isK = og >> 2;
    int o4 = (og & 3) * 4;
    int xy = chunk * 256 + lane * 4;

    const float* wsrc = isK ? kw : qw;
    const float* w0 = wsrc + (size_t)(o4 + 0) * 256;
    const float* w1 = wsrc + (size_t)(o4 + 1) * 256;
    const float* w2 = wsrc + (size_t)(o4 + 2) * 256;
    const float* w3 = wsrc + (size_t)(o4 + 3) * 256;

    float4 a0 = {0,0,0,0}, a1 = {0,0,0,0}, a2 = {0,0,0,0}, a3 = {0,0,0,0};
    const float* xb = x + (size_t)b * C_ * WH + xy;
#pragma unroll 8
    for (int c = 0; c < 256; ++c) {
        float4 xv = *(const float4*)(xb + (size_t)c * WH);
        float f0 = w0[c], f1 = w1[c], f2 = w2[c], f3 = w3[c];
        a0.x += xv.x*f0; a0.y += xv.y*f0; a0.z += xv.z*f0; a0.w += xv.w*f0;
        a1.x += xv.x*f1; a1.y += xv.y*f1; a1.z += xv.z*f1; a1.w += xv.w*f1;
        a2.x += xv.x*f2; a2.y += xv.y*f2; a2.z += xv.z*f2; a2.w += xv.w*f2;
        a3.x += xv.x*f3; a3.y += xv.y*f3; a3.z += xv.z*f3; a3.w += xv.w*f3;
    }
    float4 acc4[4] = {a0, a1, a2, a3};

    if (!isK) {
#pragma unroll
        for (int i = 0; i < 4; ++i) {
            int hk = o4 + i;
            float s  = qg[hk] * rsqrtf(qv[hk] + 1e-5f);
            float tq = qb[hk] - qm[hk] * s;
            float4 a = acc4[i], o;
            o.x = a.x * s + tq; o.y = a.y * s + tq;
            o.z = a.z * s + tq; o.w = a.w * s + tq;
            *(float4*)(qbn + ((size_t)b * 16 + hk) * WH + xy) = o;
        }
    } else {
#pragma unroll
        for (int i = 0; i < 4; ++i) {
            int hk = o4 + i;
            float s2 = kg[hk] * rsqrtf(kv[hk] + 1e-5f);
            float tk = kb[hk] - km[hk] * s2;
            float4 a = acc4[i], o;
            // unnormalized softmax numerator (proven safe r8-r10): no max-shift
            o.x = __expf(a.x * s2 + tk);
            o.y = __expf(a.y * s2 + tk);
            o.z = __expf(a.z * s2 + tk);
            o.w = __expf(a.w * s2 + tk);
            *(float4*)(ebn + ((size_t)b * 16 + hk) * WH + xy) = o;
            float ssum = o.x + o.y + o.z + o.w;
#pragma unroll
            for (int off = 32; off; off >>= 1) ssum += __shfl_xor(ssum, off, 64);
            if (lane == 0) atomicAdd(&S[b * 16 + hk], ssum);
        }
    }
}

// ---- U/T contractions via fp16 MFMA (fp32 accumulate). Round-5 proven body.
// Grid 512 = (b, s5 of 128 xy), 2 blocks/CU. W rows 0-15 = ebn * (1/S)
// (normalized at staging -> U output final-scaled), rows 16-31 = Wt.
// Tail: merged write U+T (r7-proven; valid because U is pre-normalized). ----
__global__ __launch_bounds__(512) void ut_kernel(
    const float* __restrict__ x, const float* __restrict__ ebn,
    const float* __restrict__ S, const float* __restrict__ Wt,
    float* __restrict__ Mpart)
{
    __shared__ _Float16 xls[256][72];   // 36,864 B : X rows (c), 64 k per chunk
    __shared__ _Float16 wls[32][72];    //  4,608 B : W rows (r), 64 k per chunk
    __shared__ float st[16];            // 1/S per sm row
    int t = threadIdx.x;
    int b = blockIdx.x >> 5, s5 = blockIdx.x & 31;
    int xys0 = s5 * 128;
    int lane = t & 63;
    int wid = __builtin_amdgcn_readfirstlane(t >> 6);   // 0..7
    int r16 = lane & 15, g = lane >> 4;
    int n0 = wid * 32;

    if (t < 16) st[t] = 1.f / S[b * 16 + t];

    // staging coords
    int sc = t >> 1, shalf = t & 1;                 // x: row sc, 32-col half
    int wr = t >> 3, wco = (t & 7) * 8;             // w: row wr (t<256 only)

    f32x4 acc00 = {0.f,0.f,0.f,0.f}, acc01 = {0.f,0.f,0.f,0.f};
    f32x4 acc10 = {0.f,0.f,0.f,0.f}, acc11 = {0.f,0.f,0.f,0.f};

    for (int ch = 0; ch < 2; ++ch) {
        int kbase = xys0 + ch * 64;
        __syncthreads();                            // st[] visible / prev reads done
        {   // stage X: 256 rows x 64 k  (thread: row sc, cols shalf*32..+31)
            const float* xp = x + ((size_t)b * C_ + sc) * WH + kbase + shalf * 32;
#pragma unroll
            for (int j = 0; j < 4; ++j) {
                float4 u  = *(const float4*)(xp + j * 8);
                float4 u2 = *(const float4*)(xp + j * 8 + 4);
                f16x8 o;
                o[0] = (_Float16)u.x;  o[1] = (_Float16)u.y;
                o[2] = (_Float16)u.z;  o[3] = (_Float16)u.w;
                o[4] = (_Float16)u2.x; o[5] = (_Float16)u2.y;
                o[6] = (_Float16)u2.z; o[7] = (_Float16)u2.w;
                *(f16x8*)&xls[sc][shalf * 32 + j * 8] = o;
            }
        }
        if (t < 256) {  // stage W: rows 0..15 = ebn*(1/S), 16..31 = Wt
            const float* src = (wr < 16)
                ? ebn + ((size_t)b * 16 + wr) * WH + kbase + wco
                : Wt + (size_t)(wr - 16) * WH + kbase + wco;
            float scale = (wr < 16) ? st[wr] : 1.f;
            float4 u  = *(const float4*)(src);
            float4 u2 = *(const float4*)(src + 4);
            f16x8 o;
            o[0] = (_Float16)(u.x  * scale); o[1] = (_Float16)(u.y  * scale);
            o[2] = (_Float16)(u.z  * scale); o[3] = (_Float16)(u.w  * scale);
            o[4] = (_Float16)(u2.x * scale); o[5] = (_Float16)(u2.y * scale);
            o[6] = (_Float16)(u2.z * scale); o[7] = (_Float16)(u2.w * scale);
            *(f16x8*)&wls[wr][wco] = o;
        }
        __syncthreads();                            // tile visible
#pragma unroll
        for (int s = 0; s < 2; ++s) {
            int koff = s * 32 + g * 8;
            f16x8 A0 = *(const f16x8*)&wls[r16     ][koff];
            f16x8 A1 = *(const f16x8*)&wls[16 + r16][koff];
            f16x8 B0 = *(const f16x8*)&xls[n0 + r16     ][koff];
            f16x8 B1 = *(const f16x8*)&xls[n0 + 16 + r16][koff];
            acc00 = __builtin_amdgcn_mfma_f32_16x16x32_f16(A0, B0, acc00, 0, 0, 0);
            acc01 = __builtin_amdgcn_mfma_f32_16x16x32_f16(A0, B1, acc01, 0, 0, 0);
            acc10 = __builtin_amdgcn_mfma_f32_16x16x32_f16(A1, B0, acc10, 0, 0, 0);
            acc11 = __builtin_amdgcn_mfma_f32_16x16x32_f16(A1, B1, acc11, 0, 0, 0);
        }
    }

    // ---- merged tail: row r = U_r(normalized) + T_r ----
    // D layout: row = g*4 + reg, col = n0 (+16) + r16
    float* mp = Mpart + (size_t)(b * 32 + s5) * 4096;
    int colA = n0 + r16, colB = n0 + 16 + r16;
    int row0 = g * 4;
#pragma unroll
    for (int rr = 0; rr < 4; ++rr) {
        mp[(row0 + rr) * 256 + colA] = acc00[rr] + acc10[rr];
        mp[(row0 + rr) * 256 + colB] = acc01[rr] + acc11[rr];
    }
}

// ---- lambda[b,hk,v] = sum_c v_w[h,v,c] * M[b,hk,c]. One block per (b,hk). ----
__global__ __launch_bounds__(256) void lam_kernel(
    const float* __restrict__ Mpart, const float* __restrict__ vw,
    float* __restrict__ lam)
{
    __shared__ float msum[256];
    __shared__ float vls[64][68];
    __shared__ float psum[4][64];
    int t = threadIdx.x;
    int b = blockIdx.x >> 4, hk = blockIdx.x & 15, h = hk >> 2;

    {   // msum[c] = sum over 32 merged segs (coalesced)
        const float* mp = Mpart + (size_t)b * 32 * 4096 + hk * 256 + t;
        float s = 0.f;
        for (int seg = 0; seg < 32; ++seg) s += mp[(size_t)seg * 4096];
        msum[t] = s;
    }

    int v = t & 63, cq = t >> 6;
    float acc = 0.f;
    const float* vwh = vw + (size_t)h * 64 * 256;
    for (int ch = 0; ch < 4; ++ch) {
        __syncthreads();
#pragma unroll
        for (int k = 0; k < 4; ++k) {
            int e = t + k * 256;
            int vv = e >> 4, c4 = (e & 15) * 4;
            *(float4*)&vls[vv][c4] = *(const float4*)(vwh + (size_t)vv * 256 + ch * 64 + c4);
        }
        __syncthreads();
#pragma unroll
        for (int i4 = 0; i4 < 4; ++i4) {
            float4 a  = *(const float4*)&vls[v][cq * 16 + i4 * 4];
            float4 m4 = *(const float4*)&msum[ch * 64 + cq * 16 + i4 * 4];
            acc += a.x * m4.x + a.y * m4.y + a.z * m4.z + a.w * m4.w;
        }
    }
    psum[cq][v] = acc;
    __syncthreads();
    if (t < 64)
        lam[((size_t)b * 16 + hk) * 64 + t] =
            psum[0][t] + psum[1][t] + psum[2][t] + psum[3][t];
}

// ---- out[b, h*64+v, xy] = sum_k qbn[b,hk,xy] * lam[b,hk,v]. ----
__global__ __launch_bounds__(256) void out_kernel(
    const float* __restrict__ qbn, const float* __restrict__ lam,
    float* __restrict__ out)
{
    int t = threadIdx.x;
    int b = blockIdx.x >> 4, s = blockIdx.x & 15;
    int h = s >> 2, qc = s & 3;
    int xy = qc * 1024 + t * 4;
    float4 q0 = *(const float4*)(qbn + ((size_t)b * 16 + h * 4 + 0) * WH + xy);
    float4 q1 = *(const float4*)(qbn + ((size_t)b * 16 + h * 4 + 1) * WH + xy);
    float4 q2 = *(const float4*)(qbn + ((size_t)b * 16 + h * 4 + 2) * WH + xy);
    float4 q3 = *(const float4*)(qbn + ((size_t)b * 16 + h * 4 + 3) * WH + xy);
    const float* lb = lam + (size_t)b * 1024 + (size_t)h * 256;
    float* ob = out + ((size_t)b * 256 + (size_t)h * 64) * WH + xy;
#pragma unroll 8
    for (int v = 0; v < 64; ++v) {
        float l0 = lb[v], l1 = lb[64 + v], l2 = lb[128 + v], l3 = lb[192 + v];
        float4 o;
        o.x = q0.x*l0 + q1.x*l1 + q2.x*l2 + q3.x*l3;
        o.y = q0.y*l0 + q1.y*l1 + q2.y*l2 + q3.y*l3;
        o.z = q0.z*l0 + q1.z*l1 + q2.z*l2 + q3.z*l3;
        o.w = q0.w*l0 + q1.w*l1 + q2.w*l2 + q3.w*l3;
        *(float4*)(ob + (size_t)v * WH) = o;
    }
}

extern "C" void kernel_launch(void* const* d_in, const int* in_sizes, int n_in,
                              void* d_out, int out_size, void* d_ws, size_t ws_size,
                              hipStream_t stream)
{
    const float* x   = (const float*)d_in[0];
    const float* qw  = (const float*)d_in[1];
    const float* qg  = (const float*)d_in[2];
    const float* qb  = (const float*)d_in[3];
    const float* qm  = (const float*)d_in[4];
    const float* qv  = (const float*)d_in[5];
    const float* kw  = (const float*)d_in[6];
    const float* kg  = (const float*)d_in[7];
    const float* kb  = (const float*)d_in[8];
    const float* km  = (const float*)d_in[9];
    const float* kv  = (const float*)d_in[10];
    const float* vw  = (const float*)d_in[11];
    const float* emb = (const float*)d_in[12];

    float* ws    = (float*)d_ws;
    float* qbn   = ws;
    float* ebn   = ws + 1048576;
    float* Sv    = ws + 2097152;
    float* Wt    = ws + 2097408;
    float* Mpart = ws + 2162944;
    float* lam   = ws + 4260096;
    float* out   = (float*)d_out;

    hipMemsetAsync(Sv, 0, 256 * sizeof(float), stream);
    hipLaunchKernelGGL(proj_kernel,  dim3(320), dim3(512), 0, stream,
                       x, qw, kw, qg, qb, qm, qv, kg, kb, km, kv, emb,
                       qbn, ebn, Sv, Wt);
    hipLaunchKernelGGL(ut_kernel,    dim3(512), dim3(512), 0, stream,
                       x, ebn, Sv, Wt, Mpart);
    hipLaunchKernelGGL(lam_kernel,   dim3(256), dim3(256), 0, stream, Mpart, vw, lam);
    hipLaunchKernelGGL(out_kernel,   dim3(256), dim3(256), 0, stream, qbn, lam, out);
}

// Round 12
// 74.896 us; speedup vs baseline: 1.6227x; 1.0971x over previous
//
#include <hip/hip_runtime.h>
#include <math.h>

#define C_   256
#define WH   4096

typedef _Float16 f16x8 __attribute__((ext_vector_type(8)));
typedef float    f32x4 __attribute__((ext_vector_type(4)));

// ---------------- workspace layout (floats) ----------------
// qbn   : [16][16][4096]           @ 0          (1,048,576)
// kkbn  : [16][16][4096]           @ 1,048,576  (1,048,576)
// pstats: [256 rows][32 win][2]    @ 2,097,152  (16,384)   (own slot: no alias race)
// Wt    : [16][4096]               @ 2,113,536  (65,536)
// Mpart : [16][32 s5][16][256]     @ 2,179,072  (2,097,152)  merged U(norm)+T
// lam   : [16][16][64]             @ 4,276,224  (16,384)

// ---- q/k 1x1 projections + BN + per-window softmax partials (blocks 0..255)
//      + Wt generation (blocks 256..319).
// Proj tiling: 8 waves = 2 px-halves x 4 row-groups; each wave: 8 rows x 128 px
// (float2/lane, 16 acc VGPR). Halves x-window L1 redundancy vs r5 (8x -> 4x). ----
__global__ __launch_bounds__(512) void proj_kernel(
    const float* __restrict__ x,
    const float* __restrict__ qw, const float* __restrict__ kw,
    const float* __restrict__ qg, const float* __restrict__ qb,
    const float* __restrict__ qm, const float* __restrict__ qv,
    const float* __restrict__ kg, const float* __restrict__ kb,
    const float* __restrict__ km, const float* __restrict__ kv,
    const float* __restrict__ emb,
    float* __restrict__ qbn, float* __restrict__ kkbn,
    float* __restrict__ pstats, float* __restrict__ Wt)
{
    if (blockIdx.x >= 256) {
        // ---- Wt: summed spatial weight of the positional conv (r5 verbatim) ----
        int wb = blockIdx.x - 256;
        int hk = wb >> 2, quarter = wb & 3;
        int h = hk >> 2, k = hk & 3;
        const float* e = emb + (size_t)(k * 4 + h) * 529;   // emb[k][h][0][0][i][j]
        __shared__ float colsum[23][64];
        for (int t2 = threadIdx.x; t2 < 23 * 64; t2 += 512) {
            int i = t2 / 64, q = t2 % 64;
            int jlo = max(0, q - 52), jhi = min(22, q + 11);
            float s = 0.f;
            for (int j = jlo; j <= jhi; ++j) s += e[i * 23 + j];
            colsum[i][q] = s;
        }
        __syncthreads();
        for (int tt = threadIdx.x; tt < 1024; tt += 512) {
            int t2 = quarter * 1024 + tt;
            int p = t2 >> 6, q = t2 & 63;
            int ilo = max(0, p - 52), ihi = min(22, p + 11);
            float s = 0.f;
            for (int i = ilo; i <= ihi; ++i) s += colsum[i][q];
            Wt[(size_t)hk * WH + t2] = s;
        }
        return;
    }

    int t = threadIdx.x, lane = t & 63;
    int w8 = __builtin_amdgcn_readfirstlane(t >> 6);   // 0..7, wave-uniform
    int half = w8 >> 2;           // px half: [0,128) or [128,256)
    int rg = w8 & 3;              // row group
    int isK = rg >> 1;            // 0,1 -> q rows; 2,3 -> k rows
    int r0 = (rg & 1) * 8;        // 8-row base within q or k
    int b = blockIdx.x >> 4, chunk = blockIdx.x & 15;
    int xy = chunk * 256 + half * 128 + lane * 2;

    const float* wsrc = isK ? kw : qw;
    const float* w0 = wsrc + (size_t)(r0 + 0) * 256;
    const float* w1 = wsrc + (size_t)(r0 + 1) * 256;
    const float* w2 = wsrc + (size_t)(r0 + 2) * 256;
    const float* w3 = wsrc + (size_t)(r0 + 3) * 256;
    const float* w4 = wsrc + (size_t)(r0 + 4) * 256;
    const float* w5 = wsrc + (size_t)(r0 + 5) * 256;
    const float* w6 = wsrc + (size_t)(r0 + 6) * 256;
    const float* w7 = wsrc + (size_t)(r0 + 7) * 256;

    float2 a0 = {0,0}, a1 = {0,0}, a2 = {0,0}, a3 = {0,0};
    float2 a4 = {0,0}, a5 = {0,0}, a6 = {0,0}, a7 = {0,0};
    const float* xb = x + (size_t)b * C_ * WH + xy;
#pragma unroll 8
    for (int c = 0; c < 256; ++c) {
        float2 xv = *(const float2*)(xb + (size_t)c * WH);
        float f0 = w0[c], f1 = w1[c], f2 = w2[c], f3 = w3[c];
        float f4 = w4[c], f5 = w5[c], f6 = w6[c], f7 = w7[c];
        a0.x += xv.x*f0; a0.y += xv.y*f0;  a1.x += xv.x*f1; a1.y += xv.y*f1;
        a2.x += xv.x*f2; a2.y += xv.y*f2;  a3.x += xv.x*f3; a3.y += xv.y*f3;
        a4.x += xv.x*f4; a4.y += xv.y*f4;  a5.x += xv.x*f5; a5.y += xv.y*f5;
        a6.x += xv.x*f6; a6.y += xv.y*f6;  a7.x += xv.x*f7; a7.y += xv.y*f7;
    }
    float2 acc[8] = {a0, a1, a2, a3, a4, a5, a6, a7};

    if (!isK) {
#pragma unroll
        for (int i = 0; i < 8; ++i) {
            int hk = r0 + i;
            float s  = qg[hk] * rsqrtf(qv[hk] + 1e-5f);
            float tq = qb[hk] - qm[hk] * s;
            float2 o; o.x = acc[i].x * s + tq; o.y = acc[i].y * s + tq;
            *(float2*)(qbn + ((size_t)b * 16 + hk) * WH + xy) = o;
        }
    } else {
#pragma unroll
        for (int i = 0; i < 8; ++i) {
            int hk = r0 + i;
            float s2 = kg[hk] * rsqrtf(kv[hk] + 1e-5f);
            float tk = kb[hk] - km[hk] * s2;
            float2 o; o.x = acc[i].x * s2 + tk; o.y = acc[i].y * s2 + tk;
            *(float2*)(kkbn + ((size_t)b * 16 + hk) * WH + xy) = o;
            // per-window softmax partials (window = 128 px = this wave)
            float m = fmaxf(o.x, o.y);
#pragma unroll
            for (int off = 32; off; off >>= 1) m = fmaxf(m, __shfl_xor(m, off, 64));
            float e = __expf(o.x - m) + __expf(o.y - m);
#pragma unroll
            for (int off = 32; off; off >>= 1) e += __shfl_xor(e, off, 64);
            if (lane == 0) {
                float* ps = pstats + ((size_t)(b * 16 + hk) * 32 + chunk * 2 + half) * 2;
                ps[0] = m; ps[1] = e;
            }
        }
    }
}

// ---- U/T contractions via fp16 MFMA (fp32 accumulate). Round-5 proven body
// (inline stats combine over 32 windows; W rows staged exp(kk-M)*invS, Wt).
// Tail: merged U+T write (valid: U pre-normalized at staging). ----
__global__ __launch_bounds__(512) void ut_kernel(
    const float* __restrict__ x, const float* __restrict__ kkbn,
    const float* __restrict__ pstats, const float* __restrict__ Wt,
    float* __restrict__ Mpart)
{
    __shared__ _Float16 xls[256][72];   // 36,864 B : X rows (c), 64 k per chunk
    __shared__ _Float16 wls[32][72];    //  4,608 B : W rows (r), 64 k per chunk
    __shared__ float st[32];            // M, 1/S per sm row
    int t = threadIdx.x;
    int b = blockIdx.x >> 5, s5 = blockIdx.x & 31;
    int xys0 = s5 * 128;
    int lane = t & 63;
    int wid = __builtin_amdgcn_readfirstlane(t >> 6);   // 0..7
    int r16 = lane & 15, g = lane >> 4;
    int n0 = wid * 32;

    // ---- inline softmax-stats combine: thread r<16 handles row r (32 windows) ----
    if (t < 16) {
        const float* ps = pstats + (size_t)(b * 16 + t) * 64;
        float M = ps[0];
#pragma unroll
        for (int ch = 1; ch < 32; ++ch) M = fmaxf(M, ps[ch * 2]);
        float S = 0.f;
#pragma unroll
        for (int ch = 0; ch < 32; ++ch) S += ps[ch * 2 + 1] * __expf(ps[ch * 2] - M);
        st[2 * t]     = M;
        st[2 * t + 1] = 1.f / S;
    }

    // staging coords
    int sc = t >> 1, shalf = t & 1;                 // x: row sc, 32-col half
    int wr = t >> 3, wco = (t & 7) * 8;             // w: row wr (t<256 only)

    f32x4 acc00 = {0.f,0.f,0.f,0.f}, acc01 = {0.f,0.f,0.f,0.f};
    f32x4 acc10 = {0.f,0.f,0.f,0.f}, acc11 = {0.f,0.f,0.f,0.f};

    for (int ch = 0; ch < 2; ++ch) {
        int kbase = xys0 + ch * 64;
        __syncthreads();                            // st[] visible / prev reads done
        {   // stage X: 256 rows x 64 k  (thread: row sc, cols shalf*32..+31)
            const float* xp = x + ((size_t)b * C_ + sc) * WH + kbase + shalf * 32;
#pragma unroll
            for (int j = 0; j < 4; ++j) {
                float4 u  = *(const float4*)(xp + j * 8);
                float4 u2 = *(const float4*)(xp + j * 8 + 4);
                f16x8 o;
                o[0] = (_Float16)u.x;  o[1] = (_Float16)u.y;
                o[2] = (_Float16)u.z;  o[3] = (_Float16)u.w;
                o[4] = (_Float16)u2.x; o[5] = (_Float16)u2.y;
                o[6] = (_Float16)u2.z; o[7] = (_Float16)u2.w;
                *(f16x8*)&xls[sc][shalf * 32 + j * 8] = o;
            }
        }
        if (t < 256) {  // stage W: rows 0..15 = sm(kkbn), 16..31 = Wt
            f16x8 o;
            if (wr < 16) {
                float wm   = st[2 * wr];
                float winv = st[2 * wr + 1];
                const float* src = kkbn + ((size_t)b * 16 + wr) * WH + kbase + wco;
                float4 u  = *(const float4*)(src);
                float4 u2 = *(const float4*)(src + 4);
                o[0] = (_Float16)(__expf(u.x  - wm) * winv);
                o[1] = (_Float16)(__expf(u.y  - wm) * winv);
                o[2] = (_Float16)(__expf(u.z  - wm) * winv);
                o[3] = (_Float16)(__expf(u.w  - wm) * winv);
                o[4] = (_Float16)(__expf(u2.x - wm) * winv);
                o[5] = (_Float16)(__expf(u2.y - wm) * winv);
                o[6] = (_Float16)(__expf(u2.z - wm) * winv);
                o[7] = (_Float16)(__expf(u2.w - wm) * winv);
            } else {
                const float* src = Wt + (size_t)(wr - 16) * WH + kbase + wco;
                float4 u  = *(const float4*)(src);
                float4 u2 = *(const float4*)(src + 4);
                o[0] = (_Float16)u.x;  o[1] = (_Float16)u.y;
                o[2] = (_Float16)u.z;  o[3] = (_Float16)u.w;
                o[4] = (_Float16)u2.x; o[5] = (_Float16)u2.y;
                o[6] = (_Float16)u2.z; o[7] = (_Float16)u2.w;
            }
            *(f16x8*)&wls[wr][wco] = o;
        }
        __syncthreads();                            // tile visible
#pragma unroll
        for (int s = 0; s < 2; ++s) {
            int koff = s * 32 + g * 8;
            f16x8 A0 = *(const f16x8*)&wls[r16     ][koff];
            f16x8 A1 = *(const f16x8*)&wls[16 + r16][koff];
            f16x8 B0 = *(const f16x8*)&xls[n0 + r16     ][koff];
            f16x8 B1 = *(const f16x8*)&xls[n0 + 16 + r16][koff];
            acc00 = __builtin_amdgcn_mfma_f32_16x16x32_f16(A0, B0, acc00, 0, 0, 0);
            acc01 = __builtin_amdgcn_mfma_f32_16x16x32_f16(A0, B1, acc01, 0, 0, 0);
            acc10 = __builtin_amdgcn_mfma_f32_16x16x32_f16(A1, B0, acc10, 0, 0, 0);
            acc11 = __builtin_amdgcn_mfma_f32_16x16x32_f16(A1, B1, acc11, 0, 0, 0);
        }
    }

    // ---- merged tail: row r = U_r(normalized) + T_r ----
    // D layout: row = g*4 + reg, col = n0 (+16) + r16
    float* mp = Mpart + (size_t)(b * 32 + s5) * 4096;
    int colA = n0 + r16, colB = n0 + 16 + r16;
    int row0 = g * 4;
#pragma unroll
    for (int rr = 0; rr < 4; ++rr) {
        mp[(row0 + rr) * 256 + colA] = acc00[rr] + acc10[rr];
        mp[(row0 + rr) * 256 + colB] = acc01[rr] + acc11[rr];
    }
}

// ---- lambda[b,hk,v] = sum_c v_w[h,v,c] * M[b,hk,c]. One block per (b,hk). ----
__global__ __launch_bounds__(256) void lam_kernel(
    const float* __restrict__ Mpart, const float* __restrict__ vw,
    float* __restrict__ lam)
{
    __shared__ float msum[256];
    __shared__ float vls[64][68];
    __shared__ float psum[4][64];
    int t = threadIdx.x;
    int b = blockIdx.x >> 4, hk = blockIdx.x & 15, h = hk >> 2;

    {   // msum[c] = sum over 32 merged segs (coalesced)
        const float* mp = Mpart + (size_t)b * 32 * 4096 + hk * 256 + t;
        float s = 0.f;
        for (int seg = 0; seg < 32; ++seg) s += mp[(size_t)seg * 4096];
        msum[t] = s;
    }

    int v = t & 63, cq = t >> 6;
    float acc = 0.f;
    const float* vwh = vw + (size_t)h * 64 * 256;
    for (int ch = 0; ch < 4; ++ch) {
        __syncthreads();
#pragma unroll
        for (int k = 0; k < 4; ++k) {
            int e = t + k * 256;
            int vv = e >> 4, c4 = (e & 15) * 4;
            *(float4*)&vls[vv][c4] = *(const float4*)(vwh + (size_t)vv * 256 + ch * 64 + c4);
        }
        __syncthreads();
#pragma unroll
        for (int i4 = 0; i4 < 4; ++i4) {
            float4 a  = *(const float4*)&vls[v][cq * 16 + i4 * 4];
            float4 m4 = *(const float4*)&msum[ch * 64 + cq * 16 + i4 * 4];
            acc += a.x * m4.x + a.y * m4.y + a.z * m4.z + a.w * m4.w;
        }
    }
    psum[cq][v] = acc;
    __syncthreads();
    if (t < 64)
        lam[((size_t)b * 16 + hk) * 64 + t] =
            psum[0][t] + psum[1][t] + psum[2][t] + psum[3][t];
}

// ---- out[b, h*64+v, xy] = sum_k qbn[b,hk,xy] * lam[b,hk,v]. ----
__global__ __launch_bounds__(256) void out_kernel(
    const float* __restrict__ qbn, const float* __restrict__ lam,
    float* __restrict__ out)
{
    int t = threadIdx.x;
    int b = blockIdx.x >> 4, s = blockIdx.x & 15;
    int h = s >> 2, qc = s & 3;
    int xy = qc * 1024 + t * 4;
    float4 q0 = *(const float4*)(qbn + ((size_t)b * 16 + h * 4 + 0) * WH + xy);
    float4 q1 = *(const float4*)(qbn + ((size_t)b * 16 + h * 4 + 1) * WH + xy);
    float4 q2 = *(const float4*)(qbn + ((size_t)b * 16 + h * 4 + 2) * WH + xy);
    float4 q3 = *(const float4*)(qbn + ((size_t)b * 16 + h * 4 + 3) * WH + xy);
    const float* lb = lam + (size_t)b * 1024 + (size_t)h * 256;
    float* ob = out + ((size_t)b * 256 + (size_t)h * 64) * WH + xy;
#pragma unroll 8
    for (int v = 0; v < 64; ++v) {
        float l0 = lb[v], l1 = lb[64 + v], l2 = lb[128 + v], l3 = lb[192 + v];
        float4 o;
        o.x = q0.x*l0 + q1.x*l1 + q2.x*l2 + q3.x*l3;
        o.y = q0.y*l0 + q1.y*l1 + q2.y*l2 + q3.y*l3;
        o.z = q0.z*l0 + q1.z*l1 + q2.z*l2 + q3.z*l3;
        o.w = q0.w*l0 + q1.w*l1 + q2.w*l2 + q3.w*l3;
        *(float4*)(ob + (size_t)v * WH) = o;
    }
}

extern "C" void kernel_launch(void* const* d_in, const int* in_sizes, int n_in,
                              void* d_out, int out_size, void* d_ws, size_t ws_size,
                              hipStream_t stream)
{
    const float* x   = (const float*)d_in[0];
    const float* qw  = (const float*)d_in[1];
    const float* qg  = (const float*)d_in[2];
    const float* qb  = (const float*)d_in[3];
    const float* qm  = (const float*)d_in[4];
    const float* qv  = (const float*)d_in[5];
    const float* kw  = (const float*)d_in[6];
    const float* kg  = (const float*)d_in[7];
    const float* kb  = (const float*)d_in[8];
    const float* km  = (const float*)d_in[9];
    const float* kv  = (const float*)d_in[10];
    const float* vw  = (const float*)d_in[11];
    const float* emb = (const float*)d_in[12];

    float* ws     = (float*)d_ws;
    float* qbn    = ws;
    float* kkbn   = ws + 1048576;
    float* pstats = ws + 2097152;
    float* Wt     = ws + 2113536;
    float* Mpart  = ws + 2179072;
    float* lam    = ws + 4276224;
    float* out    = (float*)d_out;

    hipLaunchKernelGGL(proj_kernel,  dim3(320), dim3(512), 0, stream,
                       x, qw, kw, qg, qb, qm, qv, kg, kb, km, kv, emb,
                       qbn, kkbn, pstats, Wt);
    hipLaunchKernelGGL(ut_kernel,    dim3(512), dim3(512), 0, stream,
                       x, kkbn, pstats, Wt, Mpart);
    hipLaunchKernelGGL(lam_kernel,   dim3(256), dim3(256), 0, stream, Mpart, vw, lam);
    hipLaunchKernelGGL(out_kernel,   dim3(256), dim3(256), 0, stream, qbn, lam, out);
}